// Round 5
// baseline (187.104 us; speedup 1.0000x reference)
//
#include <hip/hip_runtime.h>
#include <hip/hip_bf16.h>
#include <cstdint>

// CIN layer chain: B=1024, F0=32, EMB=64, layer sizes 128/128/128.
// cur[b,k,e] = sum_{i,j} x[b,i,e] * h[b,j,e] * W[i*fi+j, k]
// Per batch: C(128 x 64) = W^T (128 x fan_in) @ Z (fan_in x 64),
//   Z[(i,j),e] = x[b,i,e]*h[b,j,e]  (built on the fly in B-fragments).
//
// R5: 2 batches/block, 256 threads (4 waves = batch x m-half), grid 512,
// 2-chunk unroll, padded sH (pitch 72/40). 50 KB LDS -> 3 blocks/CU
// = 12 waves/CU = 3 waves/SIMD (R4 had ~1.3 — latency-hiding was the
// bottleneck: MfmaUtil 28%, occupancy 16%).

typedef _Float16 half8  __attribute__((ext_vector_type(8)));
typedef _Float16 half4_ __attribute__((ext_vector_type(4)));
typedef _Float16 half2_ __attribute__((ext_vector_type(2)));
typedef float    f32x4  __attribute__((ext_vector_type(4)));

__device__ __forceinline__ void load_lds16(const void* g, void* l) {
    __builtin_amdgcn_global_load_lds(
        reinterpret_cast<const __attribute__((address_space(1))) unsigned*>(
            reinterpret_cast<uintptr_t>(g)),
        reinterpret_cast<__attribute__((address_space(3))) unsigned*>(
            reinterpret_cast<uintptr_t>(l)),
        16, 0, 0);
}

__device__ __forceinline__ unsigned dupf16(float v) {
    unsigned short us = __builtin_bit_cast(unsigned short, (_Float16)v);
    return (unsigned)us * 0x10001u;
}

// Pack W (fan_in,128) f32 -> chunked f16 Wt[c][m][kk] = W[c*32+kk][m]
// (exactly the LDS A-tile layout, so staging is one contiguous 8 KB read).
__global__ void pack_w(const float* __restrict__ W, _Float16* __restrict__ Wt)
{
    __shared__ _Float16 ldsT[128 * 33];
    const int c = blockIdx.x, t = threadIdx.x;
    for (int p = t; p < 32 * 128; p += 256) {
        int kk = p >> 7, m = p & 127;
        ldsT[m * 33 + kk] = (_Float16)W[(size_t)(c * 32 + kk) * 128 + m];
    }
    __syncthreads();
    int m = t >> 1, kk0 = (t & 1) * 16;
    half8 v0, v1;
#pragma unroll
    for (int i = 0; i < 8; ++i) {
        v0[i] = ldsT[m * 33 + kk0 + i];
        v1[i] = ldsT[m * 33 + kk0 + 8 + i];
    }
    *(half8*)(Wt + (size_t)c * 4096 + t * 16)     = v0;
    *(half8*)(Wt + (size_t)c * 4096 + t * 16 + 8) = v1;
}

// One CIN layer. Block = 2 batches, 256 threads (4 waves).
// Wave w: bb=w>>1 (batch), m0=(w&1)*64 (k_out half). 64x64 C tile/wave.
__global__ __launch_bounds__(256, 3)
void cin_layer(const float* __restrict__ x,         // (1024,32,64) f32
               const _Float16* __restrict__ h_in,   // (B,64,ph) padded image, null => use x
               const _Float16* __restrict__ Wt,     // chunked [c][128][32] f16
               const float* __restrict__ bias,      // (128) f32
               _Float16* __restrict__ h_out,        // (B,64,72) padded image or null
               float* __restrict__ out,             // (1024,256) f32
               int fi, int lfi, int nchunks, int ph, int direct_m0, int out_base)
{
    __shared__ alignas(16) _Float16 sW[2 * 4096];    // 16 KB: 2 W chunks [cc][m][kk]
    __shared__ alignas(16) _Float16 sH[2 * 64 * 72]; // 18 KB: hT [bb][e*ph + j]
    __shared__ alignas(16) unsigned sX[2 * 2048];    // 16 KB: x dup-f16-pair [bb][i*64+e]

    const int t    = threadIdx.x;
    const int lane = t & 63;
    const int w    = t >> 6;
    const int lr   = lane & 15;
    const int q    = lane >> 4;
    const int b0   = blockIdx.x * 2;

    // Build packed x (dup f16 pair -> one v_pk_mul_f16 operand), float4 loads.
    {
        const float4* xv = (const float4*)(x + (size_t)b0 * 2048);
#pragma unroll
        for (int s = 0; s < 4; ++s) {
            int p4 = t + s * 256;          // 1024 float4 = 2 batches
            float4 v = xv[p4];
            uint4 d;
            d.x = dupf16(v.x); d.y = dupf16(v.y);
            d.z = dupf16(v.z); d.w = dupf16(v.w);
            *(uint4*)(sX + p4 * 4) = d;
            if (!h_in) {
                // layer 0: hidden = x; build hT [e][j], pitch ph=40
                int p0 = p4 * 4;
                int bb2 = p0 >> 11, idx = p0 & 2047;
                int i = idx >> 6, e0 = idx & 63;
                _Float16* hb = sH + bb2 * 2560;
                hb[(e0 + 0) * 40 + i] = (_Float16)v.x;
                hb[(e0 + 1) * 40 + i] = (_Float16)v.y;
                hb[(e0 + 2) * 40 + i] = (_Float16)v.z;
                hb[(e0 + 3) * 40 + i] = (_Float16)v.w;
            }
        }
    }
    if (h_in) {
        // stage 2 padded hT images (18432 B) via async global->LDS
        const char* src = (const char*)(h_in + (size_t)b0 * 4608);
        char* dst = (char*)sH;
        for (int off = t * 16; off < 18432; off += 4096)
            load_lds16(src + off, dst + off);
    }

    const int m0 = (w & 1) * 64;
    const int bb = w >> 1;

    const _Float16* aPb = sW + (m0 + lr) * 32 + q * 8;          // + cc*4096 + mt*512
    const _Float16* hP  = sH + bb * (ph << 6) + lr * ph + q * 8; // + nt*16*ph + j0
    const unsigned* xP  = sX + (bb << 11) + lr;                  // + i*64 + nt*16

    f32x4 acc[4][4] = {};

    const int niter = nchunks >> 1;
    for (int it = 0; it < niter; ++it) {
        // Stage 2 W chunks (16 KB) via async global->LDS, width 16.
        const char* wsrc = (const char*)Wt + (size_t)it * 16384 + (size_t)t * 16;
        char* wdst = (char*)sW + (size_t)t * 16;
#pragma unroll
        for (int s = 0; s < 4; ++s)
            load_lds16(wsrc + s * 4096, wdst + s * 4096);
        __syncthreads();

#pragma unroll
        for (int cc = 0; cc < 2; ++cc) {
            const int c  = it * 2 + cc;
            const int k0 = c << 5;
            const int i  = k0 >> lfi;       // which x-field this chunk covers
            const int j0 = k0 & (fi - 1);   // j offset within hidden

            const _Float16* aP = aPb + cc * 4096;
            half8 af[4];
#pragma unroll
            for (int mt = 0; mt < 4; ++mt)
                af[mt] = *(const half8*)(aP + mt * 512);

            half8 bf[4];
#pragma unroll
            for (int nt = 0; nt < 4; ++nt) {
                half8 hv = *(const half8*)(hP + nt * (ph << 4) + j0);
                half2_ xv = __builtin_bit_cast(half2_, xP[(i << 6) + (nt << 4)]);
                half8 xv8 = __builtin_shufflevector(xv, xv, 0, 1, 0, 1, 0, 1, 0, 1);
                bf[nt] = hv * xv8;
            }
#pragma unroll
            for (int mt = 0; mt < 4; ++mt)
#pragma unroll
                for (int nt = 0; nt < 4; ++nt)
                    acc[mt][nt] = __builtin_amdgcn_mfma_f32_16x16x32_f16(
                        af[mt], bf[nt], acc[mt][nt], 0, 0, 0);
        }
        __syncthreads();
    }

    const int batch = b0 + bb;

    // bias (zeros in this problem, but apply per spec)
#pragma unroll
    for (int mt = 0; mt < 4; ++mt)
#pragma unroll
        for (int r = 0; r < 4; ++r) {
            float bv = bias[m0 + mt * 16 + q * 4 + r];
#pragma unroll
            for (int nt = 0; nt < 4; ++nt) acc[mt][nt][r] += bv;
        }

    if (h_out != nullptr && m0 == 0) {
        // hidden half: write cur[b][j=m][e] transposed into padded image
        // h_out[b][e*72 + j] (f16); C/D map: col=lr, row=q*4+r (m89).
#pragma unroll
        for (int mt = 0; mt < 4; ++mt)
#pragma unroll
            for (int nt = 0; nt < 4; ++nt) {
                int e = nt * 16 + lr;
                int j = mt * 16 + q * 4;
                half4_ vh;
#pragma unroll
                for (int r = 0; r < 4; ++r) vh[r] = (_Float16)acc[mt][nt][r];
                *(half4_*)(h_out + (size_t)batch * 4608 + e * 72 + j) = vh;
            }
    } else {
        // direct half: reduce over e and write out
#pragma unroll
        for (int mt = 0; mt < 4; ++mt) {
            f32x4 s = acc[mt][0] + acc[mt][1] + acc[mt][2] + acc[mt][3];
#pragma unroll
            for (int r = 0; r < 4; ++r) {
                float v = s[r];
                v += __shfl_xor(v, 1);
                v += __shfl_xor(v, 2);
                v += __shfl_xor(v, 4);
                v += __shfl_xor(v, 8);
                if (lr == 0) {
                    int m = m0 + mt * 16 + q * 4 + r;
                    out[(size_t)batch * 256 + out_base + (m - direct_m0)] = v;
                }
            }
        }
    }
}

extern "C" void kernel_launch(void* const* d_in, const int* in_sizes, int n_in,
                              void* d_out, int out_size, void* d_ws, size_t ws_size,
                              hipStream_t stream)
{
    const float* x  = (const float*)d_in[0];
    const float* W0 = (const float*)d_in[1];
    const float* b0 = (const float*)d_in[2];
    const float* W1 = (const float*)d_in[3];
    const float* b1 = (const float*)d_in[4];
    const float* W2 = (const float*)d_in[5];
    const float* b2 = (const float*)d_in[6];
    float* out = (float*)d_out;

    char* ws = (char*)d_ws;
    _Float16* Wt0 = (_Float16*)(ws + 0);                        // 256 KB
    _Float16* Wt1 = (_Float16*)(ws + 262144);                   // 512 KB
    _Float16* Wt2 = (_Float16*)(ws + 786432);                   // 512 KB
    _Float16* h1  = (_Float16*)(ws + 1310720);                  // 1024*4608*2 = 9 MB
    _Float16* h2  = (_Float16*)(ws + 1310720 + 9437184);        // 9 MB
    (void)in_sizes; (void)n_in; (void)out_size; (void)ws_size;

    hipLaunchKernelGGL(pack_w, dim3(32), dim3(256), 0, stream, W0, Wt0);
    hipLaunchKernelGGL(pack_w, dim3(64), dim3(256), 0, stream, W1, Wt1);
    hipLaunchKernelGGL(pack_w, dim3(64), dim3(256), 0, stream, W2, Wt2);

    // layer 0: fi=32 (hidden = x), direct rows m in [64,128) -> out cols 0..63
    hipLaunchKernelGGL(cin_layer, dim3(512), dim3(256), 0, stream,
                       x, (const _Float16*)nullptr, Wt0, b0, h1, out,
                       32, 5, 32, 40, 64, 0);
    // layer 1: fi=64, direct rows -> out cols 64..127
    hipLaunchKernelGGL(cin_layer, dim3(512), dim3(256), 0, stream,
                       x, (const _Float16*)h1, Wt1, b1, h2, out,
                       64, 6, 64, 72, 64, 64);
    // layer 2: fi=64, all 128 rows direct -> out cols 128..255
    hipLaunchKernelGGL(cin_layer, dim3(512), dim3(256), 0, stream,
                       x, (const _Float16*)h2, Wt2, b2, (_Float16*)nullptr, out,
                       64, 6, 64, 72, 0, 128);
}

// Round 7
// 186.554 us; speedup vs baseline: 1.0029x; 1.0029x over previous
//
#include <hip/hip_runtime.h>
#include <hip/hip_bf16.h>
#include <cstdint>

// CIN layer chain: B=1024, F0=32, EMB=64, layer sizes 128/128/128.
// cur[b,k,e] = sum_{i,j} x[b,i,e] * h[b,j,e] * W[i*fi+j, k]
// Per batch: C(128 x 64) = W^T (128 x fan_in) @ Z (fan_in x 64),
//   Z[(i,j),e] = x[b,i,e]*h[b,j,e]  (built on the fly in B-fragments).
//
// R7: split-K (R6 structure) with LDS <= 64 KB (R6 crashed: 67584 B static
// LDS exceeded the 64 KiB/workgroup cap -> launch abort). sX now stores raw
// f16 (8 KB) and the dup-pair is rebuilt at use (1 VALU). LDS = 32 KB sW +
// 18 KB sH + 8 KB sX = 58 KB. 512 threads = 8 waves = (batch, m-half,
// K-half), grid 512 -> 4096 waves = 4 waves/SIMD (R3-R5 had 2: the
// latency-hiding wall that pinned MfmaUtil at ~27%).

typedef _Float16 half8  __attribute__((ext_vector_type(8)));
typedef _Float16 half4_ __attribute__((ext_vector_type(4)));
typedef _Float16 half2_ __attribute__((ext_vector_type(2)));
typedef float    f32x4  __attribute__((ext_vector_type(4)));
typedef unsigned short ushort4_ __attribute__((ext_vector_type(4)));

__device__ __forceinline__ void load_lds16(const void* g, void* l) {
    __builtin_amdgcn_global_load_lds(
        reinterpret_cast<const __attribute__((address_space(1))) unsigned*>(
            reinterpret_cast<uintptr_t>(g)),
        reinterpret_cast<__attribute__((address_space(3))) unsigned*>(
            reinterpret_cast<uintptr_t>(l)),
        16, 0, 0);
}

__device__ __forceinline__ unsigned short f16bits(float v) {
    return __builtin_bit_cast(unsigned short, (_Float16)v);
}

// Pack W (fan_in,128) f32 -> chunked f16 Wt[c][m][kk] = W[c*32+kk][m]
// (exactly the LDS A-tile layout, so staging is one contiguous 8 KB read).
__global__ void pack_w(const float* __restrict__ W, _Float16* __restrict__ Wt)
{
    __shared__ _Float16 ldsT[128 * 33];
    const int c = blockIdx.x, t = threadIdx.x;
    for (int p = t; p < 32 * 128; p += 256) {
        int kk = p >> 7, m = p & 127;
        ldsT[m * 33 + kk] = (_Float16)W[(size_t)(c * 32 + kk) * 128 + m];
    }
    __syncthreads();
    int m = t >> 1, kk0 = (t & 1) * 16;
    half8 v0, v1;
#pragma unroll
    for (int i = 0; i < 8; ++i) {
        v0[i] = ldsT[m * 33 + kk0 + i];
        v1[i] = ldsT[m * 33 + kk0 + 8 + i];
    }
    *(half8*)(Wt + (size_t)c * 4096 + t * 16)     = v0;
    *(half8*)(Wt + (size_t)c * 4096 + t * 16 + 8) = v1;
}

// One CIN layer. Block = 2 batches, 512 threads (8 waves).
// Wave w: ks=w&1 (K-half), mh=(w>>1)&1 (m0=mh*64), bb=w>>2 (batch).
__global__ __launch_bounds__(512, 4)
void cin_layer(const float* __restrict__ x,         // (1024,32,64) f32
               const _Float16* __restrict__ h_in,   // (B,64,72) padded image, null => use x
               const _Float16* __restrict__ Wt,     // chunked [c][128][32] f16
               const float* __restrict__ bias,      // (128) f32
               _Float16* __restrict__ h_out,        // (B,64,72) padded image or null
               float* __restrict__ out,             // (1024,256) f32
               int fi, int lfi, int nchunks, int ph, int direct_m0, int out_base)
{
    __shared__ alignas(16) char smem[59392];        // 58 KB < 64 KB cap
    _Float16* sW        = (_Float16*)smem;               // 32 KB: 4 slots x 4096 halves
    _Float16* sH        = (_Float16*)(smem + 32768);     // 18 KB: hT [bb][e*ph + j]
    unsigned short* sXu = (unsigned short*)(smem + 51200); // 8 KB: x f16 bits [bb][i*64+e]
    // epilogue reuse (all dead after the K-loop tail barrier):
    float* bufA = (float*)smem;                  // 16 KB hidden-combine bb=0 (sW slots 0,1)
    float* bufB = (float*)(smem + 16384);        // 16 KB hidden-combine bb=1 (sW slots 2,3)
    float* sRed = (float*)(smem + 32768);        // 2 KB direct partials (sH)

    const int t    = threadIdx.x;
    const int lane = t & 63;
    const int w    = t >> 6;
    const int lr   = lane & 15;
    const int q    = lane >> 4;
    const int b0   = blockIdx.x * 2;

    // Build x f16 table (and, layer 0, the hT image), float4 loads.
    {
        const float4* xv = (const float4*)(x + (size_t)b0 * 2048);
#pragma unroll
        for (int s = 0; s < 2; ++s) {
            int p4 = t + s * 512;          // 1024 float4 = 2 batches
            float4 v = xv[p4];
            ushort4_ d;
            d[0] = f16bits(v.x); d[1] = f16bits(v.y);
            d[2] = f16bits(v.z); d[3] = f16bits(v.w);
            *(ushort4_*)(sXu + p4 * 4) = d;
            if (!h_in) {
                // layer 0: hidden = x; build hT [e][j], pitch ph=40
                int p0 = p4 * 4;
                int bb2 = p0 >> 11, idx = p0 & 2047;
                int i = idx >> 6, e0 = idx & 63;
                _Float16* hb = sH + bb2 * (ph << 6);
                hb[(e0 + 0) * ph + i] = (_Float16)v.x;
                hb[(e0 + 1) * ph + i] = (_Float16)v.y;
                hb[(e0 + 2) * ph + i] = (_Float16)v.z;
                hb[(e0 + 3) * ph + i] = (_Float16)v.w;
            }
        }
    }
    if (h_in) {
        // stage 2 padded hT images (18432 B) via async global->LDS
        const char* src = (const char*)(h_in + (size_t)b0 * 4608);
        char* dst = (char*)sH;
        for (int off = t * 16; off < 18432; off += 8192)
            load_lds16(src + off, dst + off);
    }

    const int ks = w & 1;
    const int m0 = ((w >> 1) & 1) * 64;
    const int bb = w >> 2;
    const int kh = nchunks >> 1;         // chunks per K-half

    const _Float16* aPb      = sW + (m0 + lr) * 32 + q * 8;           // + slot*4096 + mt*512
    const _Float16* hP       = sH + bb * (ph << 6) + lr * ph + q * 8; // + nt*16*ph + j0
    const unsigned short* xP = sXu + (bb << 11) + lr;                 // + i*64 + nt*16

    f32x4 acc[4][4] = {};

    const int niter = nchunks >> 2;      // 2 chunks per K-half per iteration
    for (int it = 0; it < niter; ++it) {
        // Stage 4 W chunks (32 KB): slots 0,1 <- K-half 0; slots 2,3 <- K-half 1.
        const char* wsrc = (const char*)Wt;
        char* wdst = (char*)smem;
        const size_t base0 = (size_t)it * 16384;
        const size_t base1 = (size_t)kh * 8192 + (size_t)it * 16384;
        load_lds16(wsrc + base0 +        t * 16, wdst +         t * 16);
        load_lds16(wsrc + base0 + 8192 + t * 16, wdst +  8192 + t * 16);
        load_lds16(wsrc + base1 +        t * 16, wdst + 16384 + t * 16);
        load_lds16(wsrc + base1 + 8192 + t * 16, wdst + 24576 + t * 16);
        __syncthreads();

#pragma unroll
        for (int cc = 0; cc < 2; ++cc) {
            const int c    = ks * kh + it * 2 + cc;
            const int slot = ks * 2 + cc;
            const int k0   = c << 5;
            const int i    = k0 >> lfi;       // which x-field this chunk covers
            const int j0   = k0 & (fi - 1);   // j offset within hidden

            const _Float16* aP = aPb + slot * 4096;
            half8 af[4];
#pragma unroll
            for (int mt = 0; mt < 4; ++mt)
                af[mt] = *(const half8*)(aP + mt * 512);

            half8 bf[4];
#pragma unroll
            for (int nt = 0; nt < 4; ++nt) {
                half8 hv = *(const half8*)(hP + nt * (ph << 4) + j0);
                unsigned short us = xP[(i << 6) + (nt << 4)];
                unsigned du = (unsigned)us * 0x10001u;   // dup f16 into both halves
                half2_ xv2 = __builtin_bit_cast(half2_, du);
                half8 xv8 = __builtin_shufflevector(xv2, xv2, 0, 1, 0, 1, 0, 1, 0, 1);
                bf[nt] = hv * xv8;
            }
#pragma unroll
            for (int mt = 0; mt < 4; ++mt)
#pragma unroll
                for (int nt = 0; nt < 4; ++nt)
                    acc[mt][nt] = __builtin_amdgcn_mfma_f32_16x16x32_f16(
                        af[mt], bf[nt], acc[mt][nt], 0, 0, 0);
        }
        __syncthreads();
    }

    // ---- split-K combine epilogue ----
    const int batch = b0 + bb;
    const bool hidden_wave = (h_out != nullptr) && (m0 < 64) && (direct_m0 == 64);

    if (hidden_wave) {
        if (ks == 1) {
            // scatter partial to LDS: buf[e*64 + ((m+e)&63)]
            float* buf = bb ? bufB : bufA;
#pragma unroll
            for (int mt = 0; mt < 4; ++mt)
#pragma unroll
                for (int nt = 0; nt < 4; ++nt) {
                    int e = nt * 16 + lr;
#pragma unroll
                    for (int r = 0; r < 4; ++r) {
                        int m = mt * 16 + q * 4 + r;
                        buf[e * 64 + ((m + e) & 63)] = acc[mt][nt][r];
                    }
                }
        }
    } else {
        // direct wave: reduce over e (64 cols) -> per-ks partial into sRed
#pragma unroll
        for (int mt = 0; mt < 4; ++mt) {
            f32x4 s = acc[mt][0] + acc[mt][1] + acc[mt][2] + acc[mt][3];
#pragma unroll
            for (int r = 0; r < 4; ++r) {
                float v = s[r];
                v += __shfl_xor(v, 1);
                v += __shfl_xor(v, 2);
                v += __shfl_xor(v, 4);
                v += __shfl_xor(v, 8);
                if (lr == 0) {
                    int m = m0 + mt * 16 + q * 4 + r;
                    sRed[((bb * 2 + ks) << 7) + m] = v;
                }
            }
        }
    }
    __syncthreads();

    if (hidden_wave && ks == 0) {
        // combine partials, add bias, write padded f16 image
        const float* buf = bb ? bufB : bufA;
#pragma unroll
        for (int mt = 0; mt < 4; ++mt)
#pragma unroll
            for (int nt = 0; nt < 4; ++nt) {
                int e = nt * 16 + lr;
                int j = mt * 16 + q * 4;
                half4_ vh;
#pragma unroll
                for (int r = 0; r < 4; ++r) {
                    int m = j + r;
                    float v = acc[mt][nt][r] + buf[e * 64 + ((m + e) & 63)] + bias[m];
                    vh[r] = (_Float16)v;
                }
                *(half4_*)(h_out + (size_t)batch * 4608 + e * 72 + j) = vh;
            }
    }
    // direct combine: out = p(ks=0) + p(ks=1) + 64*bias
    {
        const int nd = 128 - direct_m0;
        for (int o = t; o < 2 * nd; o += 512) {
            int bb2 = (o >= nd) ? 1 : 0;
            int ml  = o - bb2 * nd;
            int m   = direct_m0 + ml;
            float v = sRed[((bb2 * 2 + 0) << 7) + m]
                    + sRed[((bb2 * 2 + 1) << 7) + m]
                    + 64.0f * bias[m];
            out[(size_t)(b0 + bb2) * 256 + out_base + ml] = v;
        }
    }
}

extern "C" void kernel_launch(void* const* d_in, const int* in_sizes, int n_in,
                              void* d_out, int out_size, void* d_ws, size_t ws_size,
                              hipStream_t stream)
{
    const float* x  = (const float*)d_in[0];
    const float* W0 = (const float*)d_in[1];
    const float* b0 = (const float*)d_in[2];
    const float* W1 = (const float*)d_in[3];
    const float* b1 = (const float*)d_in[4];
    const float* W2 = (const float*)d_in[5];
    const float* b2 = (const float*)d_in[6];
    float* out = (float*)d_out;

    char* ws = (char*)d_ws;
    _Float16* Wt0 = (_Float16*)(ws + 0);                        // 256 KB
    _Float16* Wt1 = (_Float16*)(ws + 262144);                   // 512 KB
    _Float16* Wt2 = (_Float16*)(ws + 786432);                   // 512 KB
    _Float16* h1  = (_Float16*)(ws + 1310720);                  // 1024*4608*2 = 9 MB
    _Float16* h2  = (_Float16*)(ws + 1310720 + 9437184);        // 9 MB
    (void)in_sizes; (void)n_in; (void)out_size; (void)ws_size;

    hipLaunchKernelGGL(pack_w, dim3(32), dim3(256), 0, stream, W0, Wt0);
    hipLaunchKernelGGL(pack_w, dim3(64), dim3(256), 0, stream, W1, Wt1);
    hipLaunchKernelGGL(pack_w, dim3(64), dim3(256), 0, stream, W2, Wt2);

    // layer 0: fi=32 (hidden = x), direct rows m in [64,128) -> out cols 0..63
    hipLaunchKernelGGL(cin_layer, dim3(512), dim3(512), 0, stream,
                       x, (const _Float16*)nullptr, Wt0, b0, h1, out,
                       32, 5, 32, 40, 64, 0);
    // layer 1: fi=64, direct rows -> out cols 64..127
    hipLaunchKernelGGL(cin_layer, dim3(512), dim3(512), 0, stream,
                       x, (const _Float16*)h1, Wt1, b1, h2, out,
                       64, 6, 64, 72, 64, 64);
    // layer 2: fi=64, all 128 rows direct -> out cols 128..255
    hipLaunchKernelGGL(cin_layer, dim3(512), dim3(512), 0, stream,
                       x, (const _Float16*)h2, Wt2, b2, (_Float16*)nullptr, out,
                       64, 6, 64, 72, 0, 128);
}

// Round 8
// 178.610 us; speedup vs baseline: 1.0476x; 1.0445x over previous
//
#include <hip/hip_runtime.h>
#include <hip/hip_bf16.h>
#include <cstdint>

// CIN layer chain: B=1024, F0=32, EMB=64, layer sizes 128/128/128.
// cur[b,k,e] = sum_{i,j} x[b,i,e] * h[b,j,e] * W[i*fi+j, k]
// Per batch: C(128 x 64) = W^T (128 x fan_in) @ Z (fan_in x 64),
//   Z[(i,j),e] = x[b,i,e]*h[b,j,e]  (built on the fly in B-fragments).
//
// R8: fat wave tiles. R4/R5/R7 all ~47 us at 1.3/2/4 waves/SIMD ->
// occupancy is NOT binding; LDS datapath is (~60% busy, half of it
// duplicate reads across m-half waves / bb pairs). Wave tile now
// M=128 x N=64 (acc 8x4, 128 VGPR): 12 b128 reads per 32 MFMA
// (was 24 per 32 across two waves). Block = 256 thr = 4 waves (bb x ks),
// grid 512, split-K retained, LDS 58 KB, 2 blocks/CU.

typedef _Float16 half8  __attribute__((ext_vector_type(8)));
typedef _Float16 half4_ __attribute__((ext_vector_type(4)));
typedef _Float16 half2_ __attribute__((ext_vector_type(2)));
typedef float    f32x4  __attribute__((ext_vector_type(4)));
typedef unsigned short ushort4_ __attribute__((ext_vector_type(4)));

__device__ __forceinline__ void load_lds16(const void* g, void* l) {
    __builtin_amdgcn_global_load_lds(
        reinterpret_cast<const __attribute__((address_space(1))) unsigned*>(
            reinterpret_cast<uintptr_t>(g)),
        reinterpret_cast<__attribute__((address_space(3))) unsigned*>(
            reinterpret_cast<uintptr_t>(l)),
        16, 0, 0);
}

__device__ __forceinline__ unsigned short f16bits(float v) {
    return __builtin_bit_cast(unsigned short, (_Float16)v);
}

// Pack W (fan_in,128) f32 -> chunked f16 Wt[c][m][kk] = W[c*32+kk][m]
// (exactly the LDS A-tile layout, so staging is one contiguous 8 KB read).
__global__ void pack_w(const float* __restrict__ W, _Float16* __restrict__ Wt)
{
    __shared__ _Float16 ldsT[128 * 33];
    const int c = blockIdx.x, t = threadIdx.x;
    for (int p = t; p < 32 * 128; p += 256) {
        int kk = p >> 7, m = p & 127;
        ldsT[m * 33 + kk] = (_Float16)W[(size_t)(c * 32 + kk) * 128 + m];
    }
    __syncthreads();
    int m = t >> 1, kk0 = (t & 1) * 16;
    half8 v0, v1;
#pragma unroll
    for (int i = 0; i < 8; ++i) {
        v0[i] = ldsT[m * 33 + kk0 + i];
        v1[i] = ldsT[m * 33 + kk0 + 8 + i];
    }
    *(half8*)(Wt + (size_t)c * 4096 + t * 16)     = v0;
    *(half8*)(Wt + (size_t)c * 4096 + t * 16 + 8) = v1;
}

// One CIN layer. Block = 2 batches, 256 threads (4 waves).
// Wave w: ks=w&1 (K-half), bb=w>>1 (batch). Wave tile: M=128 x N=64.
__global__ __launch_bounds__(256, 2)
void cin_layer(const float* __restrict__ x,         // (1024,32,64) f32
               const _Float16* __restrict__ h_in,   // (B,64,72) padded image, null => use x
               const _Float16* __restrict__ Wt,     // chunked [c][128][32] f16
               const float* __restrict__ bias,      // (128) f32
               _Float16* __restrict__ h_out,        // (B,64,72) padded image or null
               float* __restrict__ out,             // (1024,256) f32
               int fi, int lfi, int nchunks, int ph, int direct_m0, int out_base)
{
    __shared__ alignas(16) char smem[59392];        // 58 KB < 64 KB cap
    _Float16* sW        = (_Float16*)smem;                 // 32 KB: 4 slots x 4096 halves
    _Float16* sH        = (_Float16*)(smem + 32768);       // 18 KB: hT [bb][e*ph + j]
    unsigned short* sXu = (unsigned short*)(smem + 51200); // 8 KB: x f16 bits [bb][i*64+e]
    // epilogue reuse (all dead after the K-loop tail barrier):
    float* bufA = (float*)smem;                  // 16 KB hidden-combine bb=0
    float* bufB = (float*)(smem + 16384);        // 16 KB hidden-combine bb=1
    float* sRed = (float*)(smem + 32768);        // 2 KB direct partials

    const int t    = threadIdx.x;
    const int lane = t & 63;
    const int w    = t >> 6;
    const int lr   = lane & 15;
    const int q    = lane >> 4;
    const int b0   = blockIdx.x * 2;

    // Build x f16 table (and, layer 0, the hT image), float4 loads.
    {
        const float4* xv = (const float4*)(x + (size_t)b0 * 2048);
#pragma unroll
        for (int s = 0; s < 4; ++s) {
            int p4 = t + s * 256;          // 1024 float4 = 2 batches
            float4 v = xv[p4];
            ushort4_ d;
            d[0] = f16bits(v.x); d[1] = f16bits(v.y);
            d[2] = f16bits(v.z); d[3] = f16bits(v.w);
            *(ushort4_*)(sXu + p4 * 4) = d;
            if (!h_in) {
                // layer 0: hidden = x; build hT [e][j], pitch ph=40
                int p0 = p4 * 4;
                int bb2 = p0 >> 11, idx = p0 & 2047;
                int i = idx >> 6, e0 = idx & 63;
                _Float16* hb = sH + bb2 * (ph << 6);
                hb[(e0 + 0) * ph + i] = (_Float16)v.x;
                hb[(e0 + 1) * ph + i] = (_Float16)v.y;
                hb[(e0 + 2) * ph + i] = (_Float16)v.z;
                hb[(e0 + 3) * ph + i] = (_Float16)v.w;
            }
        }
    }
    if (h_in) {
        // stage 2 padded hT images (18432 B) via async global->LDS
        const char* src = (const char*)(h_in + (size_t)b0 * 4608);
        char* dst = (char*)sH;
        for (int off = t * 16; off < 18432; off += 4096)
            load_lds16(src + off, dst + off);
    }

    const int ks = w & 1;
    const int bb = w >> 1;
    const int kh = nchunks >> 1;         // chunks per K-half

    const _Float16* aPb      = sW + lr * 32 + q * 8;                  // + slot*4096 + mt*512
    const _Float16* hP       = sH + bb * (ph << 6) + lr * ph + q * 8; // + nt*16*ph + j0
    const unsigned short* xP = sXu + (bb << 11) + lr;                 // + i*64 + nt*16

    f32x4 acc[8][4] = {};

    const int niter = nchunks >> 2;      // 2 chunks per K-half per iteration
    for (int it = 0; it < niter; ++it) {
        // Stage 4 W chunks (32 KB): slots 0,1 <- K-half 0; slots 2,3 <- K-half 1.
        const char* wsrc = (const char*)Wt;
        char* wdst = (char*)smem;
        const size_t base0 = (size_t)it * 16384;
        const size_t base1 = (size_t)kh * 8192 + base0;
#pragma unroll
        for (int s2 = 0; s2 < 4; ++s2)
            load_lds16(wsrc + base0 + s2 * 4096 + t * 16,
                       wdst + s2 * 4096 + t * 16);
#pragma unroll
        for (int s2 = 0; s2 < 4; ++s2)
            load_lds16(wsrc + base1 + s2 * 4096 + t * 16,
                       wdst + 16384 + s2 * 4096 + t * 16);
        __syncthreads();

#pragma unroll
        for (int cc = 0; cc < 2; ++cc) {
            const int c    = ks * kh + it * 2 + cc;
            const int slot = ks * 2 + cc;
            const int k0   = c << 5;
            const int i    = k0 >> lfi;       // which x-field this chunk covers
            const int j0   = k0 & (fi - 1);   // j offset within hidden

            half8 bf[4];
#pragma unroll
            for (int nt = 0; nt < 4; ++nt) {
                half8 hv = *(const half8*)(hP + nt * (ph << 4) + j0);
                unsigned du = (unsigned)xP[(i << 6) + (nt << 4)] * 0x10001u;
                half2_ xv2 = __builtin_bit_cast(half2_, du);
                half8 xv8 = __builtin_shufflevector(xv2, xv2, 0, 1, 0, 1, 0, 1, 0, 1);
                bf[nt] = hv * xv8;
            }
            const _Float16* aP = aPb + slot * 4096;
#pragma unroll
            for (int mt = 0; mt < 8; ++mt) {
                half8 af = *(const half8*)(aP + mt * 512);
#pragma unroll
                for (int nt = 0; nt < 4; ++nt)
                    acc[mt][nt] = __builtin_amdgcn_mfma_f32_16x16x32_f16(
                        af, bf[nt], acc[mt][nt], 0, 0, 0);
            }
        }
        __syncthreads();
    }

    // ---- epilogue: split-K combine ----
    const int batch = b0 + bb;
    const bool has_hidden = (h_out != nullptr);   // layers 0,1: direct_m0==64

    // direct partials: rows m >= direct_m0, reduce over this wave's 64 e-cols
#pragma unroll
    for (int mt = 0; mt < 8; ++mt) {
        if ((mt << 4) >= direct_m0) {
            f32x4 s = acc[mt][0] + acc[mt][1] + acc[mt][2] + acc[mt][3];
#pragma unroll
            for (int r = 0; r < 4; ++r) {
                float v = s[r];
                v += __shfl_xor(v, 1);
                v += __shfl_xor(v, 2);
                v += __shfl_xor(v, 4);
                v += __shfl_xor(v, 8);
                if (lr == 0)
                    sRed[((bb * 2 + ks) << 7) + (mt << 4) + q * 4 + r] = v;
            }
        }
    }
    // hidden partial scatter (ks=1): rows 0..63 -> swizzled f32 LDS buffer
    if (has_hidden && ks == 1) {
        float* buf = bb ? bufB : bufA;
#pragma unroll
        for (int mt = 0; mt < 4; ++mt)
#pragma unroll
            for (int nt = 0; nt < 4; ++nt) {
                int e = nt * 16 + lr;
#pragma unroll
                for (int r = 0; r < 4; ++r) {
                    int m = mt * 16 + q * 4 + r;
                    buf[e * 64 + ((m + e) & 63)] = acc[mt][nt][r];
                }
            }
    }
    __syncthreads();

    if (has_hidden && ks == 0) {
        // combine K-half partials, add bias, write padded f16 image
        const float* buf = bb ? bufB : bufA;
#pragma unroll
        for (int mt = 0; mt < 4; ++mt)
#pragma unroll
            for (int nt = 0; nt < 4; ++nt) {
                int e = nt * 16 + lr;
                int j = mt * 16 + q * 4;
                half4_ vh;
#pragma unroll
                for (int r = 0; r < 4; ++r) {
                    int m = j + r;
                    float v = acc[mt][nt][r] + buf[e * 64 + ((m + e) & 63)] + bias[m];
                    vh[r] = (_Float16)v;
                }
                *(half4_*)(h_out + (size_t)batch * 4608 + e * 72 + j) = vh;
            }
    }
    // direct combine: out = p(ks=0) + p(ks=1) + 64*bias
    {
        const int nd = 128 - direct_m0;
        for (int o = t; o < 2 * nd; o += 256) {
            int bb2 = (o >= nd) ? 1 : 0;
            int ml  = o - bb2 * nd;
            int m   = direct_m0 + ml;
            float v = sRed[((bb2 * 2 + 0) << 7) + m]
                    + sRed[((bb2 * 2 + 1) << 7) + m]
                    + 64.0f * bias[m];
            out[(size_t)(b0 + bb2) * 256 + out_base + ml] = v;
        }
    }
}

extern "C" void kernel_launch(void* const* d_in, const int* in_sizes, int n_in,
                              void* d_out, int out_size, void* d_ws, size_t ws_size,
                              hipStream_t stream)
{
    const float* x  = (const float*)d_in[0];
    const float* W0 = (const float*)d_in[1];
    const float* b0 = (const float*)d_in[2];
    const float* W1 = (const float*)d_in[3];
    const float* b1 = (const float*)d_in[4];
    const float* W2 = (const float*)d_in[5];
    const float* b2 = (const float*)d_in[6];
    float* out = (float*)d_out;

    char* ws = (char*)d_ws;
    _Float16* Wt0 = (_Float16*)(ws + 0);                        // 256 KB
    _Float16* Wt1 = (_Float16*)(ws + 262144);                   // 512 KB
    _Float16* Wt2 = (_Float16*)(ws + 786432);                   // 512 KB
    _Float16* h1  = (_Float16*)(ws + 1310720);                  // 1024*4608*2 = 9 MB
    _Float16* h2  = (_Float16*)(ws + 1310720 + 9437184);        // 9 MB
    (void)in_sizes; (void)n_in; (void)out_size; (void)ws_size;

    hipLaunchKernelGGL(pack_w, dim3(32), dim3(256), 0, stream, W0, Wt0);
    hipLaunchKernelGGL(pack_w, dim3(64), dim3(256), 0, stream, W1, Wt1);
    hipLaunchKernelGGL(pack_w, dim3(64), dim3(256), 0, stream, W2, Wt2);

    // layer 0: fi=32 (hidden = x), direct rows m in [64,128) -> out cols 0..63
    hipLaunchKernelGGL(cin_layer, dim3(512), dim3(256), 0, stream,
                       x, (const _Float16*)nullptr, Wt0, b0, h1, out,
                       32, 5, 32, 40, 64, 0);
    // layer 1: fi=64, direct rows -> out cols 64..127
    hipLaunchKernelGGL(cin_layer, dim3(512), dim3(256), 0, stream,
                       x, (const _Float16*)h1, Wt1, b1, h2, out,
                       64, 6, 64, 72, 64, 64);
    // layer 2: fi=64, all 128 rows direct -> out cols 128..255
    hipLaunchKernelGGL(cin_layer, dim3(512), dim3(256), 0, stream,
                       x, (const _Float16*)h2, Wt2, b2, (_Float16*)nullptr, out,
                       64, 6, 64, 72, 0, 128);
}